// Round 3
// baseline (100.201 us; speedup 1.0000x reference)
//
#include <hip/hip_runtime.h>
#include <hip/hip_bf16.h>

// Chamfer distance between two (1,16384,3) fp32 clouds, via split-bf16
// augmented GEMM on the matrix cores:
//   A_enc[p] . B_enc[q] = |x_p|^2 + |y_q|^2 - 2 x_p.y_q = d^2(p,q)   (err ~3e-5)
// K=16 slots: [ah0,al0,ah1,al1,ah2,al2,ah0,ah1,ah2,sh,sl,1,1,0,0,0] (A side)
//             [Ah0,Ah0,Ah1,Ah1,Ah2,Ah2,Al0,Al1,Al2,1,1,sh,sl,0,0,0] (B side,
//              Ah=-2*bf16hi, Al=-2*bf16lo -- exact scalings)
// One v_mfma_f32_32x32x16_bf16 = 1024 d^2 entries; min-accumulate in C regs.
//
// V3: V2's wins (one-shot encoding precompute, pre-swizzled B layout, paired
// tiles folded via v_min3) but staging through plain coalesced
// global_load_dwordx4 + ds_write_b128 instead of global_load_lds -- the only
// V2-new construct that could plausibly fault a container. Copy is linear
// (source already in LDS layout), conflict-free, 32 KB/round.

constexpr int P      = 16384;
constexpr int BLK    = 256;
constexpr int NSEG   = 8;             // column segments per direction
constexpr int SEGPTS = P / NSEG;      // 2048 cols per block
constexpr int ROUND  = 1024;          // points staged per 32 KB LDS round
constexpr int TILES  = ROUND / 32;    // 32 MFMA col-tiles per round
constexpr int ROWSB  = 256;           // rows per block (4 waves x 64)
constexpr int CLOUDB = P * 32;        // bytes of encodings per cloud (512 KB)

typedef short s8v  __attribute__((ext_vector_type(8)));
typedef float f16v __attribute__((ext_vector_type(16)));

static __device__ inline unsigned short bf16r(float f) {   // RNE fp32->bf16
    unsigned u = __float_as_uint(f);
    u = (u + 0x7FFFu + ((u >> 16) & 1u)) >> 16;
    return (unsigned short)u;
}
static __device__ inline float bf2f(unsigned short h) {
    return __uint_as_float(((unsigned)h) << 16);
}

// A-side encoding, packed as 8 uints (16 bf16 slots, little-end first).
static __device__ inline void encA(float a, float b, float c, unsigned e[8]) {
    const unsigned ONE = 0x3F80u;
    const float s = fmaf(a, a, fmaf(b, b, c * c));
    const unsigned short ah = bf16r(a), bh = bf16r(b), ch = bf16r(c);
    const unsigned short al = bf16r(a - bf2f(ah));
    const unsigned short bl = bf16r(b - bf2f(bh));
    const unsigned short cl = bf16r(c - bf2f(ch));
    const unsigned short sh = bf16r(s), sl = bf16r(s - bf2f(sh));
    e[0] = ah | ((unsigned)al << 16);   // k0,k1
    e[1] = bh | ((unsigned)bl << 16);   // k2,k3
    e[2] = ch | ((unsigned)cl << 16);   // k4,k5
    e[3] = ah | ((unsigned)bh << 16);   // k6,k7
    e[4] = ch | ((unsigned)sh << 16);   // k8,k9
    e[5] = sl | (ONE << 16);            // k10,k11
    e[6] = ONE;                         // k12,k13(=0)
    e[7] = 0;                           // k14,k15
}

// B-side encoding (-2 folded in; all scalings exact in bf16).
static __device__ inline void encB(float a, float b, float c, unsigned e[8]) {
    const unsigned ONE = 0x3F80u;
    const float s = fmaf(a, a, fmaf(b, b, c * c));
    const unsigned short ah = bf16r(a), bh = bf16r(b), ch = bf16r(c);
    const unsigned short al = bf16r(a - bf2f(ah));
    const unsigned short bl = bf16r(b - bf2f(bh));
    const unsigned short cl = bf16r(c - bf2f(ch));
    const unsigned short sh = bf16r(s), sl = bf16r(s - bf2f(sh));
    const unsigned short Ah = bf16r(-2.f * bf2f(ah)), Bh = bf16r(-2.f * bf2f(bh));
    const unsigned short Ch = bf16r(-2.f * bf2f(ch));
    const unsigned short Al = bf16r(-2.f * bf2f(al)), Bl = bf16r(-2.f * bf2f(bl));
    const unsigned short Cl = bf16r(-2.f * bf2f(cl));
    e[0] = Ah | ((unsigned)Ah << 16);   // k0,k1
    e[1] = Bh | ((unsigned)Bh << 16);   // k2,k3
    e[2] = Ch | ((unsigned)Ch << 16);   // k4,k5
    e[3] = Al | ((unsigned)Bl << 16);   // k6,k7
    e[4] = Cl | (ONE << 16);            // k8,k9
    e[5] = ONE | ((unsigned)sh << 16);  // k10,k11
    e[6] = sl;                          // k12,k13(=0)
    e[7] = 0;                           // k14,k15
}

// ---- precompute: encode all 2x16384 points once ---------------------------
// encAbuf layout: cloud*CLOUDB + p*32 + half*16              (per-lane frag read)
// encBbuf layout: cloud*CLOUDB + (p>>5)*1024 + half*512 + (p&31)*16
//                 == the LDS ytile layout, so staging is a linear memcpy.
__global__ __launch_bounds__(BLK) void encode_pts(
    const float* __restrict__ pc1, const float* __restrict__ pc2,
    unsigned char* __restrict__ encAbuf, unsigned char* __restrict__ encBbuf,
    float* __restrict__ out)
{
    const int gid = blockIdx.x * BLK + threadIdx.x;   // 0 .. 2P-1
    if (gid == 0) out[0] = 0.0f;
    const int c = gid >> 14;                          // cloud
    const int p = gid & (P - 1);
    const float* src = c ? pc2 : pc1;
    const float x = src[3 * p], y = src[3 * p + 1], z = src[3 * p + 2];

    unsigned ea[8], eb[8];
    encA(x, y, z, ea);
    encB(x, y, z, eb);

    unsigned char* ap = encAbuf + (size_t)c * CLOUDB + (size_t)p * 32;
    *(uint4*)(ap)      = make_uint4(ea[0], ea[1], ea[2], ea[3]);
    *(uint4*)(ap + 16) = make_uint4(ea[4], ea[5], ea[6], ea[7]);

    unsigned char* bp = encBbuf + (size_t)c * CLOUDB + (size_t)(p >> 5) * 1024
                        + (size_t)(p & 31) * 16;
    *(uint4*)(bp)       = make_uint4(eb[0], eb[1], eb[2], eb[3]);
    *(uint4*)(bp + 512) = make_uint4(eb[4], eb[5], eb[6], eb[7]);
}

// ---- main: per (rowgroup, segment, dir) strip-sweep GEMM with min-acc ------
__global__ __launch_bounds__(BLK, 4) void chamfer_mfma(
    const unsigned char* __restrict__ encAbuf,
    const unsigned char* __restrict__ encBbuf,
    float* __restrict__ part)       // [2][NSEG][P], every slot written once
{
    const int dir = blockIdx.z;
    const int acloud = dir;          // dir0: rows from pc1
    const int bcloud = dir ^ 1;      // dir0: cols from pc2

    __shared__ __align__(16) unsigned char ytile[ROUND * 32];  // 32 KB

    const int tid  = threadIdx.x;
    const int lane = tid & 63;
    const int wv   = tid >> 6;
    const int l31  = lane & 31;
    const int half = lane >> 5;          // k-half for A/B frags

    // ---- A fragments: 2 strips of 32 rows per wave, loaded once ----
    const int rowbase = blockIdx.x * ROWSB + wv * 64;
    const unsigned char* abase = encAbuf + (size_t)acloud * CLOUDB + (size_t)half * 16;
    s8v afrag[2];
    #pragma unroll
    for (int s = 0; s < 2; ++s)
        afrag[s] = *(const s8v*)(abase + (size_t)(rowbase + s * 32 + l31) * 32);

    f16v acc0, acc1, Z;
    #pragma unroll
    for (int i = 0; i < 16; ++i) { acc0[i] = 3.0e38f; acc1[i] = 3.0e38f; Z[i] = 0.0f; }

    const int segbase = blockIdx.y * SEGPTS;
    for (int r = 0; r < SEGPTS / ROUND; ++r) {
        // ---- stage ROUND col-points: pure linear coalesced copy
        //      (source pre-swizzled to LDS layout by encode_pts)
        const uint4* gs = (const uint4*)(encBbuf + (size_t)bcloud * CLOUDB
                                         + (size_t)(segbase + r * ROUND) * 32);
        uint4* ls = (uint4*)ytile;
        #pragma unroll 4
        for (int j = 0; j < 8; ++j) {
            const int idx = tid + j * BLK;        // 2048 x 16B = 32 KB
            ls[idx] = gs[idx];
        }
        __syncthreads();

        const unsigned char* rp = ytile + lane * 16;   // conflict-free b128
        #pragma unroll 2
        for (int t = 0; t < TILES; t += 2) {
            const s8v b0 = *(const s8v*)(rp + t * 1024);
            const s8v b1 = *(const s8v*)(rp + t * 1024 + 1024);
            const f16v d0a = __builtin_amdgcn_mfma_f32_32x32x16_bf16(afrag[0], b0, Z, 0, 0, 0);
            const f16v d0b = __builtin_amdgcn_mfma_f32_32x32x16_bf16(afrag[0], b1, Z, 0, 0, 0);
            #pragma unroll
            for (int i = 0; i < 16; ++i)               // -> v_min3_f32
                acc0[i] = fminf(acc0[i], fminf(d0a[i], d0b[i]));
            const f16v d1a = __builtin_amdgcn_mfma_f32_32x32x16_bf16(afrag[1], b0, Z, 0, 0, 0);
            const f16v d1b = __builtin_amdgcn_mfma_f32_32x32x16_bf16(afrag[1], b1, Z, 0, 0, 0);
            #pragma unroll
            for (int i = 0; i < 16; ++i)
                acc1[i] = fminf(acc1[i], fminf(d1a[i], d1b[i]));
        }
        __syncthreads();
    }

    // ---- fold over the 32 columns held across lanes; write per-row min ----
    // C/D layout (verified): col=lane&31, row=(reg&3)+8*(reg>>2)+4*(lane>>5)
    float* pbase = part + ((size_t)(dir * NSEG + blockIdx.y)) * P;
    #pragma unroll
    for (int s = 0; s < 2; ++s) {
        #pragma unroll
        for (int rg = 0; rg < 16; ++rg) {
            float v = s ? acc1[rg] : acc0[rg];
            v = fminf(v, __shfl_xor(v, 1, 64));
            v = fminf(v, __shfl_xor(v, 2, 64));
            v = fminf(v, __shfl_xor(v, 4, 64));
            v = fminf(v, __shfl_xor(v, 8, 64));
            v = fminf(v, __shfl_xor(v, 16, 64));
            if (l31 == 0) {
                const int row = rowbase + s * 32 + (rg & 3) + 8 * (rg >> 2) + 4 * half;
                pbase[row] = v;
            }
        }
    }
}

// ---- reduce: min over segments, threshold, mean, atomic sum ----------------
__global__ __launch_bounds__(BLK) void chamfer_reduce(
    const float* __restrict__ part, float* __restrict__ out)
{
    const int gid = blockIdx.x * BLK + threadIdx.x;   // 0 .. 2P-1
    const int dirbase = (gid >= P) ? NSEG * P : 0;
    const int row = gid & (P - 1);

    float m = part[dirbase + row];
    #pragma unroll
    for (int s = 1; s < NSEG; ++s) m = fminf(m, part[dirbase + s * P + row]);

    if (m >= 2.0f) m = 0.0f;                  // DIST_THD mask
    float v = m * (1.0f / (float)P);          // point mean; batch N=1

    #pragma unroll
    for (int off = 32; off > 0; off >>= 1) v += __shfl_down(v, off, 64);

    __shared__ float wsum[BLK / 64];
    const int lane = threadIdx.x & 63;
    const int wvi = threadIdx.x >> 6;
    if (lane == 0) wsum[wvi] = v;
    __syncthreads();
    if (threadIdx.x == 0) {
        float ssum = wsum[0];
        #pragma unroll
        for (int w = 1; w < BLK / 64; ++w) ssum += wsum[w];
        atomicAdd(out, ssum);
    }
}

extern "C" void kernel_launch(void* const* d_in, const int* in_sizes, int n_in,
                              void* d_out, int out_size, void* d_ws, size_t ws_size,
                              hipStream_t stream) {
    const float* pc1 = (const float*)d_in[0];
    const float* pc2 = (const float*)d_in[1];
    float* out = (float*)d_out;
    unsigned char* ws = (unsigned char*)d_ws;
    float* part = (float*)ws;                           // 1 MB
    unsigned char* encBbuf = ws + (1u << 20);           // 1 MB
    unsigned char* encAbuf = ws + (2u << 20);           // 1 MB

    encode_pts<<<(2 * P) / BLK, BLK, 0, stream>>>(pc1, pc2, encAbuf, encBbuf, out);

    dim3 grid(P / ROWSB, NSEG, 2);            // 64 x 8 x 2 = 1024 blocks
    chamfer_mfma<<<grid, BLK, 0, stream>>>(encAbuf, encBbuf, part);
    chamfer_reduce<<<(2 * P) / BLK, BLK, 0, stream>>>(part, out);
}

// Round 4
// 88.115 us; speedup vs baseline: 1.1372x; 1.1372x over previous
//
#include <hip/hip_runtime.h>
#include <hip/hip_bf16.h>

// Chamfer distance between two (1,16384,3) fp32 clouds, via split-bf16
// augmented GEMM on the matrix cores:
//   A_enc[p] . B_enc[q] = |x_p|^2 + |y_q|^2 - 2 x_p.y_q = d^2(p,q)   (err ~3e-5)
// One v_mfma_f32_32x32x16_bf16 = 1024 d^2 entries; min-accumulate in C regs.
//
// V4: occupancy-focused restructure. V3's counters: MfmaUtil 14%, VALUBusy 56%,
// Occupancy 27% -- stall-bound at ~2 waves/SIMD because live AGPR-class state
// (Z + 2 acc + 4 MFMA results = 112) + 60 VGPR ~ 188/wave vs 512 unified.
//  - NSEG 8->16: one 32KB staging round per block, 2048 finer-grained blocks.
//  - strip-serial tile-pairing: per strip, 2 MFMAs then one min3 fold, so only
//    ~2 result f16vs live at a time -> ~140 regs/wave -> 3 waves/SIMD.
//  - keeps: precomputed encodings (no per-block re-encode), pre-swizzled B
//    layout (linear conflict-free staging), min3 fold (8 ops/MFMA).

constexpr int P      = 16384;
constexpr int BLK    = 256;
constexpr int NSEG   = 16;            // column segments per direction
constexpr int SEGPTS = P / NSEG;      // 1024 cols per block (one LDS round)
constexpr int ROUND  = 1024;          // points staged per 32 KB LDS round
constexpr int TILES  = ROUND / 32;    // 32 MFMA col-tiles per round
constexpr int ROWSB  = 256;           // rows per block (4 waves x 64)
constexpr int CLOUDB = P * 32;        // bytes of encodings per cloud (512 KB)

typedef short s8v  __attribute__((ext_vector_type(8)));
typedef float f16v __attribute__((ext_vector_type(16)));

static __device__ inline unsigned short bf16r(float f) {   // RNE fp32->bf16
    unsigned u = __float_as_uint(f);
    u = (u + 0x7FFFu + ((u >> 16) & 1u)) >> 16;
    return (unsigned short)u;
}
static __device__ inline float bf2f(unsigned short h) {
    return __uint_as_float(((unsigned)h) << 16);
}

// A-side encoding, packed as 8 uints (16 bf16 slots, little-end first).
static __device__ inline void encA(float a, float b, float c, unsigned e[8]) {
    const unsigned ONE = 0x3F80u;
    const float s = fmaf(a, a, fmaf(b, b, c * c));
    const unsigned short ah = bf16r(a), bh = bf16r(b), ch = bf16r(c);
    const unsigned short al = bf16r(a - bf2f(ah));
    const unsigned short bl = bf16r(b - bf2f(bh));
    const unsigned short cl = bf16r(c - bf2f(ch));
    const unsigned short sh = bf16r(s), sl = bf16r(s - bf2f(sh));
    e[0] = ah | ((unsigned)al << 16);   // k0,k1
    e[1] = bh | ((unsigned)bl << 16);   // k2,k3
    e[2] = ch | ((unsigned)cl << 16);   // k4,k5
    e[3] = ah | ((unsigned)bh << 16);   // k6,k7
    e[4] = ch | ((unsigned)sh << 16);   // k8,k9
    e[5] = sl | (ONE << 16);            // k10,k11
    e[6] = ONE;                         // k12,k13(=0)
    e[7] = 0;                           // k14,k15
}

// B-side encoding (-2 folded in; all scalings exact in bf16).
static __device__ inline void encB(float a, float b, float c, unsigned e[8]) {
    const unsigned ONE = 0x3F80u;
    const float s = fmaf(a, a, fmaf(b, b, c * c));
    const unsigned short ah = bf16r(a), bh = bf16r(b), ch = bf16r(c);
    const unsigned short al = bf16r(a - bf2f(ah));
    const unsigned short bl = bf16r(b - bf2f(bh));
    const unsigned short cl = bf16r(c - bf2f(ch));
    const unsigned short sh = bf16r(s), sl = bf16r(s - bf2f(sh));
    const unsigned short Ah = bf16r(-2.f * bf2f(ah)), Bh = bf16r(-2.f * bf2f(bh));
    const unsigned short Ch = bf16r(-2.f * bf2f(ch));
    const unsigned short Al = bf16r(-2.f * bf2f(al)), Bl = bf16r(-2.f * bf2f(bl));
    const unsigned short Cl = bf16r(-2.f * bf2f(cl));
    e[0] = Ah | ((unsigned)Ah << 16);   // k0,k1
    e[1] = Bh | ((unsigned)Bh << 16);   // k2,k3
    e[2] = Ch | ((unsigned)Ch << 16);   // k4,k5
    e[3] = Al | ((unsigned)Bl << 16);   // k6,k7
    e[4] = Cl | (ONE << 16);            // k8,k9
    e[5] = ONE | ((unsigned)sh << 16);  // k10,k11
    e[6] = sl;                          // k12,k13(=0)
    e[7] = 0;                           // k14,k15
}

// ---- precompute: encode all 2x16384 points once ---------------------------
// encAbuf layout: cloud*CLOUDB + p*32 + half*16              (per-lane frag read)
// encBbuf layout: cloud*CLOUDB + (p>>5)*1024 + half*512 + (p&31)*16
//                 == the LDS ytile layout, so staging is a linear memcpy.
__global__ __launch_bounds__(BLK) void encode_pts(
    const float* __restrict__ pc1, const float* __restrict__ pc2,
    unsigned char* __restrict__ encAbuf, unsigned char* __restrict__ encBbuf,
    float* __restrict__ out)
{
    const int gid = blockIdx.x * BLK + threadIdx.x;   // 0 .. 2P-1
    if (gid == 0) out[0] = 0.0f;
    const int c = gid >> 14;                          // cloud
    const int p = gid & (P - 1);
    const float* src = c ? pc2 : pc1;
    const float x = src[3 * p], y = src[3 * p + 1], z = src[3 * p + 2];

    unsigned ea[8], eb[8];
    encA(x, y, z, ea);
    encB(x, y, z, eb);

    unsigned char* ap = encAbuf + (size_t)c * CLOUDB + (size_t)p * 32;
    *(uint4*)(ap)      = make_uint4(ea[0], ea[1], ea[2], ea[3]);
    *(uint4*)(ap + 16) = make_uint4(ea[4], ea[5], ea[6], ea[7]);

    unsigned char* bp = encBbuf + (size_t)c * CLOUDB + (size_t)(p >> 5) * 1024
                        + (size_t)(p & 31) * 16;
    *(uint4*)(bp)       = make_uint4(eb[0], eb[1], eb[2], eb[3]);
    *(uint4*)(bp + 512) = make_uint4(eb[4], eb[5], eb[6], eb[7]);
}

// ---- main: per (rowgroup, segment, dir) strip-sweep GEMM with min-acc ------
__global__ __launch_bounds__(BLK, 4) void chamfer_mfma(
    const unsigned char* __restrict__ encAbuf,
    const unsigned char* __restrict__ encBbuf,
    float* __restrict__ part)       // [2][NSEG][P], every slot written once
{
    const int dir = blockIdx.z;
    const int acloud = dir;          // dir0: rows from pc1
    const int bcloud = dir ^ 1;      // dir0: cols from pc2

    __shared__ __align__(16) unsigned char ytile[ROUND * 32];  // 32 KB

    const int tid  = threadIdx.x;
    const int lane = tid & 63;
    const int wv   = tid >> 6;
    const int l31  = lane & 31;
    const int half = lane >> 5;          // k-half for A/B frags

    // ---- A fragments: 2 strips of 32 rows per wave, loaded once ----
    const int rowbase = blockIdx.x * ROWSB + wv * 64;
    const unsigned char* abase = encAbuf + (size_t)acloud * CLOUDB + (size_t)half * 16;
    s8v afrag0 = *(const s8v*)(abase + (size_t)(rowbase + l31) * 32);
    s8v afrag1 = *(const s8v*)(abase + (size_t)(rowbase + 32 + l31) * 32);

    // ---- stage the block's 1024 col-points: linear coalesced 32 KB copy
    //      (source pre-swizzled to LDS layout by encode_pts)
    {
        const uint4* gs = (const uint4*)(encBbuf + (size_t)bcloud * CLOUDB
                                         + (size_t)(blockIdx.y * SEGPTS) * 32);
        uint4* ls = (uint4*)ytile;
        #pragma unroll
        for (int j = 0; j < 8; ++j) {
            const int idx = tid + j * BLK;        // 2048 x 16B = 32 KB
            ls[idx] = gs[idx];
        }
    }

    f16v acc0, acc1, Z;
    #pragma unroll
    for (int i = 0; i < 16; ++i) { acc0[i] = 3.0e38f; acc1[i] = 3.0e38f; Z[i] = 0.0f; }

    __syncthreads();

    const unsigned char* rp = ytile + lane * 16;   // conflict-free b128
    for (int t = 0; t < TILES; t += 2) {
        const s8v b0 = *(const s8v*)(rp + t * 1024);
        const s8v b1 = *(const s8v*)(rp + t * 1024 + 1024);
        // strip 0: pair of MFMAs, one min3 fold (keeps <=2 results live)
        {
            const f16v da = __builtin_amdgcn_mfma_f32_32x32x16_bf16(afrag0, b0, Z, 0, 0, 0);
            const f16v db = __builtin_amdgcn_mfma_f32_32x32x16_bf16(afrag0, b1, Z, 0, 0, 0);
            #pragma unroll
            for (int i = 0; i < 16; ++i)           // -> v_min3_f32
                acc0[i] = fminf(acc0[i], fminf(da[i], db[i]));
        }
        // strip 1
        {
            const f16v da = __builtin_amdgcn_mfma_f32_32x32x16_bf16(afrag1, b0, Z, 0, 0, 0);
            const f16v db = __builtin_amdgcn_mfma_f32_32x32x16_bf16(afrag1, b1, Z, 0, 0, 0);
            #pragma unroll
            for (int i = 0; i < 16; ++i)
                acc1[i] = fminf(acc1[i], fminf(da[i], db[i]));
        }
    }

    // ---- fold over the 32 columns held across lanes; write per-row min ----
    // C/D layout (verified): col=lane&31, row=(reg&3)+8*(reg>>2)+4*(lane>>5)
    float* pbase = part + ((size_t)(dir * NSEG + blockIdx.y)) * P;
    #pragma unroll
    for (int s = 0; s < 2; ++s) {
        #pragma unroll
        for (int rg = 0; rg < 16; ++rg) {
            float v = s ? acc1[rg] : acc0[rg];
            v = fminf(v, __shfl_xor(v, 1, 64));
            v = fminf(v, __shfl_xor(v, 2, 64));
            v = fminf(v, __shfl_xor(v, 4, 64));
            v = fminf(v, __shfl_xor(v, 8, 64));
            v = fminf(v, __shfl_xor(v, 16, 64));
            if (l31 == 0) {
                const int row = rowbase + s * 32 + (rg & 3) + 8 * (rg >> 2) + 4 * half;
                pbase[row] = v;
            }
        }
    }
}

// ---- reduce: min over segments, threshold, mean, atomic sum ----------------
__global__ __launch_bounds__(BLK) void chamfer_reduce(
    const float* __restrict__ part, float* __restrict__ out)
{
    const int gid = blockIdx.x * BLK + threadIdx.x;   // 0 .. 2P-1
    const int dirbase = (gid >= P) ? NSEG * P : 0;
    const int row = gid & (P - 1);

    float m = part[dirbase + row];
    #pragma unroll
    for (int s = 1; s < NSEG; ++s) m = fminf(m, part[dirbase + s * P + row]);

    if (m >= 2.0f) m = 0.0f;                  // DIST_THD mask
    float v = m * (1.0f / (float)P);          // point mean; batch N=1

    #pragma unroll
    for (int off = 32; off > 0; off >>= 1) v += __shfl_down(v, off, 64);

    __shared__ float wsum[BLK / 64];
    const int lane = threadIdx.x & 63;
    const int wvi = threadIdx.x >> 6;
    if (lane == 0) wsum[wvi] = v;
    __syncthreads();
    if (threadIdx.x == 0) {
        float ssum = wsum[0];
        #pragma unroll
        for (int w = 1; w < BLK / 64; ++w) ssum += wsum[w];
        atomicAdd(out, ssum);
    }
}

extern "C" void kernel_launch(void* const* d_in, const int* in_sizes, int n_in,
                              void* d_out, int out_size, void* d_ws, size_t ws_size,
                              hipStream_t stream) {
    const float* pc1 = (const float*)d_in[0];
    const float* pc2 = (const float*)d_in[1];
    float* out = (float*)d_out;
    unsigned char* ws = (unsigned char*)d_ws;
    float* part = (float*)ws;                           // [2][16][P] = 2 MB
    unsigned char* encBbuf = ws + (2u << 20);           // 1 MB
    unsigned char* encAbuf = ws + (3u << 20);           // 1 MB

    encode_pts<<<(2 * P) / BLK, BLK, 0, stream>>>(pc1, pc2, encAbuf, encBbuf, out);

    dim3 grid(P / ROWSB, NSEG, 2);            // 64 x 16 x 2 = 2048 blocks
    chamfer_mfma<<<grid, BLK, 0, stream>>>(encAbuf, encBbuf, part);
    chamfer_reduce<<<(2 * P) / BLK, BLK, 0, stream>>>(part, out);
}